// Round 16
// baseline (4171.286 us; speedup 1.0000x reference)
//
#include <hip/hip_runtime.h>
#include <math.h>

constexpr int kT = 512;
constexpr int kC = 1024;
constexpr int kD = 512;

typedef __attribute__((ext_vector_type(8))) short bf16x8;
typedef __attribute__((ext_vector_type(4))) float f32x4;
typedef __attribute__((ext_vector_type(4))) unsigned int u32x4;

__device__ __forceinline__ float b2f(unsigned short u) {
  unsigned int v = ((unsigned int)u) << 16;
  return __builtin_bit_cast(float, v);
}
__device__ __forceinline__ unsigned short f2b(float f) {
  unsigned int u = __builtin_bit_cast(unsigned int, f);
  u += 0x7fffu + ((u >> 16) & 1u);
  return (unsigned short)(u >> 16);
}
__device__ __forceinline__ float sigm(float x) {
  x = fminf(15.f, fmaxf(-15.f, x));
  return 1.f / (1.f + __expf(-x));
}
__device__ __forceinline__ float tanh_(float x) {
  x = fminf(15.f, fmaxf(-15.f, x));
  float e2 = __expf(2.f * x);
  return (e2 - 1.f) / (e2 + 1.f);
}
__device__ __forceinline__ float efun(float s) {
  // exp(CLAMP*0.636*atan(s/CLAMP)), CLAMP=5
  return __expf((5.0f * 0.636f) * atanf(s * 0.2f));
}

// write-through-to-MALL stores (non-atomic -> coalesce; no L2 allocate/RFO)
__device__ __forceinline__ void st_b16_wt(unsigned short* p, unsigned short v) {
  asm volatile("global_store_short %0, %1, off sc0 sc1" ::"v"(p),
               "v"((unsigned int)v)
               : "memory");
}
__device__ __forceinline__ void st_f32_wt(float* p, float v) {
  asm volatile("global_store_dword %0, %1, off sc0 sc1" ::"v"(p), "v"(v)
               : "memory");
}

__device__ __forceinline__ unsigned int ldflag(const unsigned int* p) {
  return __hip_atomic_load(p, __ATOMIC_RELAXED, __HIP_MEMORY_SCOPE_AGENT);
}

// x[:, :, D:] fp32 -> xb2[t][b][512] bf16
__global__ __launch_bounds__(256) void cvt_x2_kernel(
    const float* __restrict__ x, unsigned short* __restrict__ xb2) {
  const int idx = blockIdx.x * 256 + threadIdx.x;  // one per 8 elems
  const int e = idx * 8;
  const int dd = e & 511;
  const int tb = e >> 9;
  const int b = tb & 63;
  const int t = tb >> 6;
  const float* src = x + ((size_t)b * kT + t) * kC + kD + dd;
  f32x4 v0 = *(const f32x4*)src;
  f32x4 v1 = *(const f32x4*)(src + 4);
  bf16x8 o;
#pragma unroll
  for (int j = 0; j < 4; j++) {
    o[j] = (short)f2b(v0[j]);
    o[j + 4] = (short)f2b(v1[j]);
  }
  *(bf16x8*)(xb2 + e) = o;
}

// One persistent kernel, 128 blocks x 256 threads (r14 base, proven 3497us).
// Blocks 0..63   = chain A (s2 GRU / y1 / y1o, out[:, :, :512]), superstep s = it
// Blocks 64..127 = chain B (s1 GRU / y2,       out[:, :, 512:]), superstep s, it = s-2
// Per-wave plane decoupling (no in-loop barriers): wave w only produces and
// consumes h/y1/x rows [16w,16w+16), syncing with plane-w peers only via its
// own 128B flag line (relaxed agent atomic store; consumer gather poll with
// >= — monotonic, overtake-safe). x-first MFMA split (r14).
// Diffs vs r14 (both pure poll reorderings):
//  1) chain B: the two serial polls (A-flags, then B-flags) merge into ONE
//     combined dual-gather wait on the conjunction; y1 and h loads then issue
//     together so their MALL RTs overlap. Removes one detect RT per step from
//     the pacing chain.
//  2) both chains: the NEXT step's flag gather is issued in the post-flag
//     tail and checked first at loop top — for the straggler block (the
//     per-step makespan) the carried gather already passes, removing the
//     detect RT exactly on the critical path.
__global__ __launch_bounds__(256, 1) void fused_glow_kernel(
    const float* __restrict__ x, const unsigned short* __restrict__ xb2,
    const float* __restrict__ A_Wih, const float* __restrict__ A_Whh,
    const float* __restrict__ A_bih, const float* __restrict__ A_bhh,
    const float* __restrict__ A_Wo, const float* __restrict__ A_bo,
    const float* __restrict__ A_cgW, const float* __restrict__ A_cgb,
    const float* __restrict__ B_Wih, const float* __restrict__ B_Whh,
    const float* __restrict__ B_bih, const float* __restrict__ B_bhh,
    const float* __restrict__ B_Wo, const float* __restrict__ B_bo,
    const float* __restrict__ B_cgW, const float* __restrict__ B_cgb,
    unsigned short* __restrict__ y1buf, float* __restrict__ out,
    unsigned short* __restrict__ hbA, unsigned short* __restrict__ hbB,
    unsigned int* __restrict__ flagsA, unsigned int* __restrict__ flagsB) {
  const int g = blockIdx.x;
  const bool isA = (g < 64);
  const int gl = isA ? g : (g - 64);
  const int tid = threadIdx.x;
  const int w = tid >> 6;
  const int l = tid & 63;
  const int q = l & 15;
  const int kg = l >> 4;
  const bool lo = (q < 8);
  const int qm = q & 7;
  const int d = 8 * gl + qm;
  const int browbase = 16 * w + 4 * kg;
  const int arow = 16 * w + q;
  const int acol = kg * 8;

  const float* Wih = isA ? A_Wih : B_Wih;
  const float* Whh = isA ? A_Whh : B_Whh;
  const float* bih = isA ? A_bih : B_bih;
  const float* bhh = isA ? A_bhh : B_bhh;
  const float* Wo = isA ? A_Wo : B_Wo;
  const float* bo = isA ? A_bo : B_bo;
  const float* cgW = isA ? A_cgW : B_cgW;
  const float* cgb = isA ? A_cgb : B_cgb;
  unsigned short* hbuf = isA ? hbA : hbB;
  // per-(chain, plane, block) flag line (128B stride) — r11 layout
  unsigned int* myflag =
      (isA ? flagsA : flagsB) + ((size_t)w * 64 + gl) * 32;
  const unsigned int* fpA = flagsA + (size_t)w * 64 * 32 + (size_t)l * 32;
  const unsigned int* fpB = flagsB + (size_t)w * 64 * 32 + (size_t)l * 32;

  // ---- stage 72 weight rows (+8 zero rows) as bf16, 4-bit-XOR-swizzled 16B
  __shared__ __attribute__((aligned(16))) unsigned short wlds[80 * 512];
  for (int c = tid; c < 80 * 64; c += 256) {
    const int u = c >> 6, kb = c & 63;
    const int s8 = 8 * gl + (u & 7);
    const int sel = u >> 3;
    u32x4 v = {0u, 0u, 0u, 0u};
    if (sel < 9) {
      const float* wrp = (sel == 0)   ? Whh + (size_t)s8 * kD
                         : (sel == 1) ? Whh + (size_t)(512 + s8) * kD
                         : (sel == 2) ? Whh + (size_t)(1024 + s8) * kD
                         : (sel == 3) ? cgW + (size_t)s8 * kD
                         : (sel == 4) ? Wo + (size_t)s8 * kD
                         : (sel == 5) ? Wo + (size_t)(512 + s8) * kD
                         : (sel == 6) ? Wih + (size_t)s8 * kD
                         : (sel == 7) ? Wih + (size_t)(512 + s8) * kD
                                      : Wih + (size_t)(1024 + s8) * kD;
      const float* p = wrp + kb * 8;
#pragma unroll
      for (int j = 0; j < 4; j++)
        v[j] = (unsigned int)f2b(p[2 * j]) | ((unsigned int)f2b(p[2 * j + 1]) << 16);
    }
    const int byteoff = u * 1024 + ((kb * 16) ^ ((u & 15) << 4));
    *(u32x4*)((char*)wlds + byteoff) = v;
  }

  float biasv[5];
  biasv[0] = lo ? bhh[d] : bhh[512 + d];
  biasv[1] = lo ? bhh[1024 + d] : cgb[d];
  biasv[2] = lo ? bo[d] : bo[512 + d];
  biasv[3] = lo ? bih[d] : bih[512 + d];
  biasv[4] = lo ? bih[1024 + d] : 0.f;

  float hsl[4] = {0.f, 0.f, 0.f, 0.f};
  float ecp[4];
#pragma unroll
  for (int r = 0; r < 4; r++) ecp[r] = efun(cgb[d]);

  __syncthreads();  // LDS staging complete (only barrier in the kernel)

  const int sw = q << 4;
  const int s0 = isA ? 0 : 2;
  const int s1 = isA ? 512 : 514;
  unsigned int va_pre = 0, vb_pre = 0;  // carried pre-gathered flag values
#pragma unroll 1
  for (int s = s0; s <= s1; ++s) {
    const int it = isA ? s : (s - 2);

    bf16x8 ax[16];
    float xopf[4] = {0.f, 0.f, 0.f, 0.f};
    if (isA) {
      // x-side loads are input-only: issue BEFORE the poll to hide latency
      const int itc = it < 511 ? it : 511;
      const unsigned short* xp = xb2 + ((size_t)itc * 64 + arow) * 512 + acol;
#pragma unroll
      for (int kk = 0; kk < 16; kk++) ax[kk] = *(const bf16x8*)(xp + kk * 32);
      if (lo) {
        const int ttc = s >= 1 ? s - 1 : 0;
#pragma unroll
        for (int r = 0; r < 4; r++)
          xopf[r] = x[(size_t)(browbase + r) * (kT * kC) + (size_t)ttc * kC + d];
      }
      if (s >= 1) {  // check the carried pre-gather first, then poll
        unsigned int v = va_pre;
        while (!__all((int)(v >= (unsigned)s))) {
          __builtin_amdgcn_s_sleep(1);
          v = ldflag(fpA);
        }
      }
    } else {
      if (lo) {
        const int ttc = it >= 1 ? it - 1 : 0;
#pragma unroll
        for (int r = 0; r < 4; r++)
          xopf[r] =
              x[(size_t)(browbase + r) * (kT * kC) + (size_t)ttc * kC + kD + d];
      }
      // combined dual-poll: wait for A plane-w (y1(it) ready) AND B plane-w
      // peers (h(it) ready) in one loop — both gathers in flight concurrently
      const unsigned int tgtA = (unsigned)(s <= 513 ? s : 513);
      const unsigned int tgtB = (unsigned)(s >= 3 ? s : 0);
      {
        unsigned int va = va_pre, vb = vb_pre;
        while (!(__all((int)(va >= tgtA)) && __all((int)(vb >= tgtB)))) {
          __builtin_amdgcn_s_sleep(1);
          va = ldflag(fpA);
          vb = ldflag(fpB);
        }
      }
      // issue y1 loads now; h loads issue right after (RTs overlap)
      const int ity = it < 511 ? it : 511;
      const unsigned short* yp = y1buf + ((size_t)ity * 64 + arow) * 512 + acol;
#pragma unroll
      for (int kk = 0; kk < 16; kk++) ax[kk] = *(const bf16x8*)(yp + kk * 32);
    }

    // ---- issue h(prev) fragment loads (slot s (A) / it (B); slot 0 zeroed)
    const unsigned short* hp =
        hbuf + (size_t)(isA ? s : it) * 32768 + (size_t)arow * 512 + acol;
    bf16x8 ah[16];
#pragma unroll
    for (int kk = 0; kk < 16; kk++) ah[kk] = *(const bf16x8*)(hp + kk * 32);

    // ---- x-side MFMA (tiles 3,4): runs while ah (and B's ax tail) in flight
    f32x4 acc3 = {0.f, 0.f, 0.f, 0.f}, acc4 = {0.f, 0.f, 0.f, 0.f};
#pragma unroll
    for (int kk = 0; kk < 16; kk++) {
      const int kbyte = (kk * 32 + kg * 8) * 2;
      bf16x8 b3 =
          *(const bf16x8*)((const char*)wlds + (48 + q) * 1024 + (kbyte ^ sw));
      bf16x8 b4 =
          *(const bf16x8*)((const char*)wlds + (64 + q) * 1024 + (kbyte ^ sw));
      acc3 = __builtin_amdgcn_mfma_f32_16x16x32_bf16(ax[kk], b3, acc3, 0, 0, 0);
      acc4 = __builtin_amdgcn_mfma_f32_16x16x32_bf16(ax[kk], b4, acc4, 0, 0, 0);
    }
    // ---- h-side MFMA (tiles 0-2)
    f32x4 acc0 = {0.f, 0.f, 0.f, 0.f}, acc1 = {0.f, 0.f, 0.f, 0.f};
    f32x4 acc2 = {0.f, 0.f, 0.f, 0.f};
#pragma unroll
    for (int kk = 0; kk < 16; kk++) {
      const int kbyte = (kk * 32 + kg * 8) * 2;
      bf16x8 b0 = *(const bf16x8*)((const char*)wlds + q * 1024 + (kbyte ^ sw));
      bf16x8 b1 =
          *(const bf16x8*)((const char*)wlds + (16 + q) * 1024 + (kbyte ^ sw));
      bf16x8 b2 =
          *(const bf16x8*)((const char*)wlds + (32 + q) * 1024 + (kbyte ^ sw));
      acc0 = __builtin_amdgcn_mfma_f32_16x16x32_bf16(ah[kk], b0, acc0, 0, 0, 0);
      acc1 = __builtin_amdgcn_mfma_f32_16x16x32_bf16(ah[kk], b1, acc1, 0, 0, 0);
      acc2 = __builtin_amdgcn_mfma_f32_16x16x32_bf16(ah[kk], b2, acc2, 0, 0, 0);
    }

    float ab0[4], ab1[4], ab2[4], ab3[4], ab4[4];
#pragma unroll
    for (int r = 0; r < 4; r++) {
      ab0[r] = acc0[r] + biasv[0];  // lo: gh_r   hi: gh_z
      ab1[r] = acc1[r] + biasv[1];  // lo: gh_n   hi: c
      ab2[r] = acc2[r] + biasv[2];  // lo: s      hi: t
      ab3[r] = acc3[r] + biasv[3];  // lo: gi_r   hi: gi_z
      ab4[r] = acc4[r] + biasv[4];  // lo: gi_n   hi: unused
    }
    float ghz[4], tv[4], giz[4], ec_sh[4];
#pragma unroll
    for (int r = 0; r < 4; r++) {
      ghz[r] = __shfl_xor(ab0[r], 8, 64);
      tv[r] = __shfl_xor(ab2[r], 8, 64);
      giz[r] = __shfl_xor(ab3[r], 8, 64);
      ec_sh[r] = __shfl_xor(ecp[r], 8, 64);  // e(c) from previous superstep
    }

    // ---- pre-flag: state + exchange (y1/h) stores only
    const int tt = it - 1;
    float yvs[4] = {0.f, 0.f, 0.f, 0.f};
    if (lo) {
#pragma unroll
      for (int r = 0; r < 4; r++) {
        const int b = browbase + r;
        if (isA && it >= 1) {
          yvs[r] = efun(ab2[r]) * xopf[r] + tv[r];  // y1 = e(s2v)*x1 + t2
          st_b16_wt(y1buf + ((size_t)tt * 64 + b) * 512 + d, f2b(yvs[r]));
        }
        if (it <= 511) {
          const float rr = sigm(ab3[r] + ab0[r]);
          const float zz = sigm(giz[r] + ghz[r]);
          const float nn = tanh_(ab4[r] + rr * ab1[r]);
          const float hn = (1.f - zz) * nn + zz * hsl[r];
          hsl[r] = hn;
          st_b16_wt(hbuf + (size_t)(it + 1) * 32768 + (size_t)b * 512 + d,
                    f2b(hn));
        }
      }
    } else {
#pragma unroll
      for (int r = 0; r < 4; r++) ecp[r] = efun(ab1[r]);  // e(c(it))
    }

    // ---- arrival: per-wave drain of exchange stores, then this wave's flag
    asm volatile("s_waitcnt vmcnt(0)" ::: "memory");
    if (l == 0)
      __hip_atomic_store(myflag, (unsigned)(s + 1), __ATOMIC_RELAXED,
                         __HIP_MEMORY_SCOPE_AGENT);

    // ---- post-flag: pre-issue next step's flag gather (checked at loop top;
    //      its RT overlaps the out-stores + loop overhead), then out-stores
    va_pre = ldflag(fpA);
    if (!isA) vb_pre = ldflag(fpB);
    if (lo && it >= 1) {
#pragma unroll
      for (int r = 0; r < 4; r++) {
        const int b = browbase + r;
        float* op =
            out + (size_t)b * (kT * kC) + (size_t)tt * kC + (isA ? 0 : kD) + d;
        if (isA) {
          st_f32_wt(op, yvs[r] * ec_sh[r]);  // y1o = y1 * e(c2)
        } else {
          st_f32_wt(op, efun(ab2[r]) * (xopf[r] * ec_sh[r]) + tv[r]);  // y2
        }
      }
    }
  }
}

extern "C" void kernel_launch(void* const* d_in, const int* in_sizes, int n_in,
                              void* d_out, int out_size, void* d_ws, size_t ws_size,
                              hipStream_t stream) {
  (void)in_sizes; (void)n_in; (void)out_size; (void)ws_size;
  const float* x = (const float*)d_in[0];
  const float* s1_Wih = (const float*)d_in[1];
  const float* s1_Whh = (const float*)d_in[2];
  const float* s1_bih = (const float*)d_in[3];
  const float* s1_bhh = (const float*)d_in[4];
  const float* s1_Wo = (const float*)d_in[5];
  const float* s1_bo = (const float*)d_in[6];
  const float* s2_Wih = (const float*)d_in[7];
  const float* s2_Whh = (const float*)d_in[8];
  const float* s2_bih = (const float*)d_in[9];
  const float* s2_bhh = (const float*)d_in[10];
  const float* s2_Wo = (const float*)d_in[11];
  const float* s2_bo = (const float*)d_in[12];
  const float* cg1_W = (const float*)d_in[13];
  const float* cg1_b = (const float*)d_in[14];
  const float* cg2_W = (const float*)d_in[15];
  const float* cg2_b = (const float*)d_in[16];
  float* out = (float*)d_out;
  char* ws = (char*)d_ws;

  // ws layout (bytes):
  //   xb2   @ 0          : T*B*512 bf16   = 33,554,432
  //   y1    @ 33554432   : T*B*512 bf16   = 33,554,432
  //   hbA   @ 67108864   : 513*B*512 bf16 = 33,619,968
  //   hbB   @ 100728832  : 33,619,968
  //   flags @ 134348800  : flagsA[4 planes][64 blk][32 u32] = 32KB, flagsB +32KB
  unsigned short* xb2 = (unsigned short*)ws;
  unsigned short* y1b = (unsigned short*)(ws + 33554432);
  unsigned short* hbA = (unsigned short*)(ws + 67108864);
  unsigned short* hbB = (unsigned short*)(ws + 100728832);
  unsigned int* flagsA = (unsigned int*)(ws + 134348800);
  unsigned int* flagsB = (unsigned int*)(ws + 134348800 + 32768);

  // zero: h slot 0 for both chains + flags
  hipMemsetAsync(ws + 67108864, 0, 65536, stream);
  hipMemsetAsync(ws + 100728832, 0, 65536, stream);
  hipMemsetAsync(ws + 134348800, 0, 65536, stream);

  cvt_x2_kernel<<<8192, 256, 0, stream>>>(x, xb2);

  fused_glow_kernel<<<128, 256, 0, stream>>>(
      x, xb2,
      // chain A = s2 + cg2
      s2_Wih, s2_Whh, s2_bih, s2_bhh, s2_Wo, s2_bo, cg2_W, cg2_b,
      // chain B = s1 + cg1
      s1_Wih, s1_Whh, s1_bih, s1_bhh, s1_Wo, s1_bo, cg1_W, cg1_b,
      y1b, out, hbA, hbB, flagsA, flagsB);
}

// Round 17
// 3494.324 us; speedup vs baseline: 1.1937x; 1.1937x over previous
//
#include <hip/hip_runtime.h>
#include <math.h>

constexpr int kT = 512;
constexpr int kC = 1024;
constexpr int kD = 512;

typedef __attribute__((ext_vector_type(8))) short bf16x8;
typedef __attribute__((ext_vector_type(4))) float f32x4;
typedef __attribute__((ext_vector_type(4))) unsigned int u32x4;

__device__ __forceinline__ float b2f(unsigned short u) {
  unsigned int v = ((unsigned int)u) << 16;
  return __builtin_bit_cast(float, v);
}
__device__ __forceinline__ unsigned short f2b(float f) {
  unsigned int u = __builtin_bit_cast(unsigned int, f);
  u += 0x7fffu + ((u >> 16) & 1u);
  return (unsigned short)(u >> 16);
}
__device__ __forceinline__ float sigm(float x) {
  x = fminf(15.f, fmaxf(-15.f, x));
  return 1.f / (1.f + __expf(-x));
}
__device__ __forceinline__ float tanh_(float x) {
  x = fminf(15.f, fmaxf(-15.f, x));
  float e2 = __expf(2.f * x);
  return (e2 - 1.f) / (e2 + 1.f);
}
__device__ __forceinline__ float efun(float s) {
  // exp(CLAMP*0.636*atan(s/CLAMP)), CLAMP=5
  return __expf((5.0f * 0.636f) * atanf(s * 0.2f));
}

// write-through-to-MALL stores (non-atomic -> coalesce; no L2 allocate/RFO)
__device__ __forceinline__ void st_b16_wt(unsigned short* p, unsigned short v) {
  asm volatile("global_store_short %0, %1, off sc0 sc1" ::"v"(p),
               "v"((unsigned int)v)
               : "memory");
}
__device__ __forceinline__ void st_f32_wt(float* p, float v) {
  asm volatile("global_store_dword %0, %1, off sc0 sc1" ::"v"(p), "v"(v)
               : "memory");
}

__device__ __forceinline__ unsigned int ldflag(const unsigned int* p) {
  return __hip_atomic_load(p, __ATOMIC_RELAXED, __HIP_MEMORY_SCOPE_AGENT);
}

// x[:, :, D:] fp32 -> xb2[t][b][512] bf16
__global__ __launch_bounds__(256) void cvt_x2_kernel(
    const float* __restrict__ x, unsigned short* __restrict__ xb2) {
  const int idx = blockIdx.x * 256 + threadIdx.x;  // one per 8 elems
  const int e = idx * 8;
  const int dd = e & 511;
  const int tb = e >> 9;
  const int b = tb & 63;
  const int t = tb >> 6;
  const float* src = x + ((size_t)b * kT + t) * kC + kD + dd;
  f32x4 v0 = *(const f32x4*)src;
  f32x4 v1 = *(const f32x4*)(src + 4);
  bf16x8 o;
#pragma unroll
  for (int j = 0; j < 4; j++) {
    o[j] = (short)f2b(v0[j]);
    o[j + 4] = (short)f2b(v1[j]);
  }
  *(bf16x8*)(xb2 + e) = o;
}

// One persistent kernel, 128 blocks x 256 threads (r14 configuration — the
// best-proven variant of this session, 3497us; final).
// Blocks 0..63   = chain A (s2 GRU / y1 / y1o, out[:, :, :512]), superstep s = it
// Blocks 64..127 = chain B (s1 GRU / y2,       out[:, :, 512:]), superstep s, it = s-2
// Per-wave plane decoupling (no in-loop barriers): wave w only produces and
// consumes h/y1/x rows [16w,16w+16), syncing with plane-w peers only via its
// own 128B flag line (relaxed agent atomic store; consumer 64-line gather
// poll with >= — monotonic, overtake-safe). x-first MFMA split: issue the h
// fragment loads, run tiles 3/4 (ax x LDS weights, pre-polled inputs) while
// ah is in flight, then tiles 0-2 (pure h). Exchange: per-timestep fresh
// buffers, sc0sc1 write-through stores, per-wave vmcnt(0) drain, flag store;
// pure out[] stores deferred past the flag.
__global__ __launch_bounds__(256, 1) void fused_glow_kernel(
    const float* __restrict__ x, const unsigned short* __restrict__ xb2,
    const float* __restrict__ A_Wih, const float* __restrict__ A_Whh,
    const float* __restrict__ A_bih, const float* __restrict__ A_bhh,
    const float* __restrict__ A_Wo, const float* __restrict__ A_bo,
    const float* __restrict__ A_cgW, const float* __restrict__ A_cgb,
    const float* __restrict__ B_Wih, const float* __restrict__ B_Whh,
    const float* __restrict__ B_bih, const float* __restrict__ B_bhh,
    const float* __restrict__ B_Wo, const float* __restrict__ B_bo,
    const float* __restrict__ B_cgW, const float* __restrict__ B_cgb,
    unsigned short* __restrict__ y1buf, float* __restrict__ out,
    unsigned short* __restrict__ hbA, unsigned short* __restrict__ hbB,
    unsigned int* __restrict__ flagsA, unsigned int* __restrict__ flagsB) {
  const int g = blockIdx.x;
  const bool isA = (g < 64);
  const int gl = isA ? g : (g - 64);
  const int tid = threadIdx.x;
  const int w = tid >> 6;
  const int l = tid & 63;
  const int q = l & 15;
  const int kg = l >> 4;
  const bool lo = (q < 8);
  const int qm = q & 7;
  const int d = 8 * gl + qm;
  const int browbase = 16 * w + 4 * kg;
  const int arow = 16 * w + q;
  const int acol = kg * 8;

  const float* Wih = isA ? A_Wih : B_Wih;
  const float* Whh = isA ? A_Whh : B_Whh;
  const float* bih = isA ? A_bih : B_bih;
  const float* bhh = isA ? A_bhh : B_bhh;
  const float* Wo = isA ? A_Wo : B_Wo;
  const float* bo = isA ? A_bo : B_bo;
  const float* cgW = isA ? A_cgW : B_cgW;
  const float* cgb = isA ? A_cgb : B_cgb;
  unsigned short* hbuf = isA ? hbA : hbB;
  // per-(chain, plane, block) flag line (128B stride)
  unsigned int* myflag =
      (isA ? flagsA : flagsB) + ((size_t)w * 64 + gl) * 32;
  const unsigned int* pollA = flagsA + (size_t)w * 64 * 32;  // + l*32
  const unsigned int* pollB = flagsB + (size_t)w * 64 * 32;

  // ---- stage 72 weight rows (+8 zero rows) as bf16, 4-bit-XOR-swizzled 16B
  __shared__ __attribute__((aligned(16))) unsigned short wlds[80 * 512];
  for (int c = tid; c < 80 * 64; c += 256) {
    const int u = c >> 6, kb = c & 63;
    const int s8 = 8 * gl + (u & 7);
    const int sel = u >> 3;
    u32x4 v = {0u, 0u, 0u, 0u};
    if (sel < 9) {
      const float* wrp = (sel == 0)   ? Whh + (size_t)s8 * kD
                         : (sel == 1) ? Whh + (size_t)(512 + s8) * kD
                         : (sel == 2) ? Whh + (size_t)(1024 + s8) * kD
                         : (sel == 3) ? cgW + (size_t)s8 * kD
                         : (sel == 4) ? Wo + (size_t)s8 * kD
                         : (sel == 5) ? Wo + (size_t)(512 + s8) * kD
                         : (sel == 6) ? Wih + (size_t)s8 * kD
                         : (sel == 7) ? Wih + (size_t)(512 + s8) * kD
                                      : Wih + (size_t)(1024 + s8) * kD;
      const float* p = wrp + kb * 8;
#pragma unroll
      for (int j = 0; j < 4; j++)
        v[j] = (unsigned int)f2b(p[2 * j]) | ((unsigned int)f2b(p[2 * j + 1]) << 16);
    }
    const int byteoff = u * 1024 + ((kb * 16) ^ ((u & 15) << 4));
    *(u32x4*)((char*)wlds + byteoff) = v;
  }

  float biasv[5];
  biasv[0] = lo ? bhh[d] : bhh[512 + d];
  biasv[1] = lo ? bhh[1024 + d] : cgb[d];
  biasv[2] = lo ? bo[d] : bo[512 + d];
  biasv[3] = lo ? bih[d] : bih[512 + d];
  biasv[4] = lo ? bih[1024 + d] : 0.f;

  float hsl[4] = {0.f, 0.f, 0.f, 0.f};
  float ecp[4];
#pragma unroll
  for (int r = 0; r < 4; r++) ecp[r] = efun(cgb[d]);

  __syncthreads();  // LDS staging complete (only barrier in the kernel)

  const int sw = q << 4;
  const int s0 = isA ? 0 : 2;
  const int s1 = isA ? 512 : 514;
#pragma unroll 1
  for (int s = s0; s <= s1; ++s) {
    const int it = isA ? s : (s - 2);

    bf16x8 ax[16];
    float xopf[4] = {0.f, 0.f, 0.f, 0.f};
    if (isA) {
      // x-side loads are input-only: issue BEFORE the poll to hide latency
      const int itc = it < 511 ? it : 511;
      const unsigned short* xp = xb2 + ((size_t)itc * 64 + arow) * 512 + acol;
#pragma unroll
      for (int kk = 0; kk < 16; kk++) ax[kk] = *(const bf16x8*)(xp + kk * 32);
      if (lo) {
        const int ttc = s >= 1 ? s - 1 : 0;
#pragma unroll
        for (int r = 0; r < 4; r++)
          xopf[r] = x[(size_t)(browbase + r) * (kT * kC) + (size_t)ttc * kC + d];
      }
      if (s >= 1) {  // per-wave poll of this plane's 64 A-flag lines
        const unsigned int* fp = pollA + (size_t)l * 32;
        unsigned int v = ldflag(fp);
        while (!__all((int)(v >= (unsigned)s))) {
          __builtin_amdgcn_s_sleep(1);
          v = ldflag(fp);
        }
      }
    } else {
      if (lo) {
        const int ttc = it >= 1 ? it - 1 : 0;
#pragma unroll
        for (int r = 0; r < 4; r++)
          xopf[r] =
              x[(size_t)(browbase + r) * (kT * kC) + (size_t)ttc * kC + kD + d];
      }
      // phase 1: wait for A plane-w (y1(it) rows [16w,16w+16) ready)
      {
        const unsigned int tgtA = (unsigned)(s <= 513 ? s : 513);
        const unsigned int* fp = pollA + (size_t)l * 32;
        unsigned int v = ldflag(fp);
        while (!__all((int)(v >= tgtA))) {
          __builtin_amdgcn_s_sleep(1);
          v = ldflag(fp);
        }
      }
      // issue y1 loads before waiting on B plane peers
      const int ity = it < 511 ? it : 511;
      const unsigned short* yp = y1buf + ((size_t)ity * 64 + arow) * 512 + acol;
#pragma unroll
      for (int kk = 0; kk < 16; kk++) ax[kk] = *(const bf16x8*)(yp + kk * 32);
      if (s >= 3) {
        const unsigned int* fp = pollB + (size_t)l * 32;
        unsigned int v = ldflag(fp);
        while (!__all((int)(v >= (unsigned)s))) {
          __builtin_amdgcn_s_sleep(1);
          v = ldflag(fp);
        }
      }
    }

    // ---- issue h(prev) fragment loads (slot s (A) / it (B); slot 0 zeroed)
    const unsigned short* hp =
        hbuf + (size_t)(isA ? s : it) * 32768 + (size_t)arow * 512 + acol;
    bf16x8 ah[16];
#pragma unroll
    for (int kk = 0; kk < 16; kk++) ah[kk] = *(const bf16x8*)(hp + kk * 32);

    // ---- x-side MFMA (tiles 3,4): inputs pre-polled; runs while ah in flight
    f32x4 acc3 = {0.f, 0.f, 0.f, 0.f}, acc4 = {0.f, 0.f, 0.f, 0.f};
#pragma unroll
    for (int kk = 0; kk < 16; kk++) {
      const int kbyte = (kk * 32 + kg * 8) * 2;
      bf16x8 b3 =
          *(const bf16x8*)((const char*)wlds + (48 + q) * 1024 + (kbyte ^ sw));
      bf16x8 b4 =
          *(const bf16x8*)((const char*)wlds + (64 + q) * 1024 + (kbyte ^ sw));
      acc3 = __builtin_amdgcn_mfma_f32_16x16x32_bf16(ax[kk], b3, acc3, 0, 0, 0);
      acc4 = __builtin_amdgcn_mfma_f32_16x16x32_bf16(ax[kk], b4, acc4, 0, 0, 0);
    }
    // ---- h-side MFMA (tiles 0-2)
    f32x4 acc0 = {0.f, 0.f, 0.f, 0.f}, acc1 = {0.f, 0.f, 0.f, 0.f};
    f32x4 acc2 = {0.f, 0.f, 0.f, 0.f};
#pragma unroll
    for (int kk = 0; kk < 16; kk++) {
      const int kbyte = (kk * 32 + kg * 8) * 2;
      bf16x8 b0 = *(const bf16x8*)((const char*)wlds + q * 1024 + (kbyte ^ sw));
      bf16x8 b1 =
          *(const bf16x8*)((const char*)wlds + (16 + q) * 1024 + (kbyte ^ sw));
      bf16x8 b2 =
          *(const bf16x8*)((const char*)wlds + (32 + q) * 1024 + (kbyte ^ sw));
      acc0 = __builtin_amdgcn_mfma_f32_16x16x32_bf16(ah[kk], b0, acc0, 0, 0, 0);
      acc1 = __builtin_amdgcn_mfma_f32_16x16x32_bf16(ah[kk], b1, acc1, 0, 0, 0);
      acc2 = __builtin_amdgcn_mfma_f32_16x16x32_bf16(ah[kk], b2, acc2, 0, 0, 0);
    }

    float ab0[4], ab1[4], ab2[4], ab3[4], ab4[4];
#pragma unroll
    for (int r = 0; r < 4; r++) {
      ab0[r] = acc0[r] + biasv[0];  // lo: gh_r   hi: gh_z
      ab1[r] = acc1[r] + biasv[1];  // lo: gh_n   hi: c
      ab2[r] = acc2[r] + biasv[2];  // lo: s      hi: t
      ab3[r] = acc3[r] + biasv[3];  // lo: gi_r   hi: gi_z
      ab4[r] = acc4[r] + biasv[4];  // lo: gi_n   hi: unused
    }
    float ghz[4], tv[4], giz[4], ec_sh[4];
#pragma unroll
    for (int r = 0; r < 4; r++) {
      ghz[r] = __shfl_xor(ab0[r], 8, 64);
      tv[r] = __shfl_xor(ab2[r], 8, 64);
      giz[r] = __shfl_xor(ab3[r], 8, 64);
      ec_sh[r] = __shfl_xor(ecp[r], 8, 64);  // e(c) from previous superstep
    }

    // ---- pre-flag: state + exchange (y1/h) stores only
    const int tt = it - 1;
    float yvs[4] = {0.f, 0.f, 0.f, 0.f};
    if (lo) {
#pragma unroll
      for (int r = 0; r < 4; r++) {
        const int b = browbase + r;
        if (isA && it >= 1) {
          yvs[r] = efun(ab2[r]) * xopf[r] + tv[r];  // y1 = e(s2v)*x1 + t2
          st_b16_wt(y1buf + ((size_t)tt * 64 + b) * 512 + d, f2b(yvs[r]));
        }
        if (it <= 511) {
          const float rr = sigm(ab3[r] + ab0[r]);
          const float zz = sigm(giz[r] + ghz[r]);
          const float nn = tanh_(ab4[r] + rr * ab1[r]);
          const float hn = (1.f - zz) * nn + zz * hsl[r];
          hsl[r] = hn;
          st_b16_wt(hbuf + (size_t)(it + 1) * 32768 + (size_t)b * 512 + d,
                    f2b(hn));
        }
      }
    } else {
#pragma unroll
      for (int r = 0; r < 4; r++) ecp[r] = efun(ab1[r]);  // e(c(it))
    }

    // ---- arrival: per-wave drain of exchange stores, then this wave's flag
    asm volatile("s_waitcnt vmcnt(0)" ::: "memory");
    if (l == 0)
      __hip_atomic_store(myflag, (unsigned)(s + 1), __ATOMIC_RELAXED,
                         __HIP_MEMORY_SCOPE_AGENT);

    // ---- post-flag: pure-output stores (nobody reads these)
    if (lo && it >= 1) {
#pragma unroll
      for (int r = 0; r < 4; r++) {
        const int b = browbase + r;
        float* op =
            out + (size_t)b * (kT * kC) + (size_t)tt * kC + (isA ? 0 : kD) + d;
        if (isA) {
          st_f32_wt(op, yvs[r] * ec_sh[r]);  // y1o = y1 * e(c2)
        } else {
          st_f32_wt(op, efun(ab2[r]) * (xopf[r] * ec_sh[r]) + tv[r]);  // y2
        }
      }
    }
  }
}

extern "C" void kernel_launch(void* const* d_in, const int* in_sizes, int n_in,
                              void* d_out, int out_size, void* d_ws, size_t ws_size,
                              hipStream_t stream) {
  (void)in_sizes; (void)n_in; (void)out_size; (void)ws_size;
  const float* x = (const float*)d_in[0];
  const float* s1_Wih = (const float*)d_in[1];
  const float* s1_Whh = (const float*)d_in[2];
  const float* s1_bih = (const float*)d_in[3];
  const float* s1_bhh = (const float*)d_in[4];
  const float* s1_Wo = (const float*)d_in[5];
  const float* s1_bo = (const float*)d_in[6];
  const float* s2_Wih = (const float*)d_in[7];
  const float* s2_Whh = (const float*)d_in[8];
  const float* s2_bih = (const float*)d_in[9];
  const float* s2_bhh = (const float*)d_in[10];
  const float* s2_Wo = (const float*)d_in[11];
  const float* s2_bo = (const float*)d_in[12];
  const float* cg1_W = (const float*)d_in[13];
  const float* cg1_b = (const float*)d_in[14];
  const float* cg2_W = (const float*)d_in[15];
  const float* cg2_b = (const float*)d_in[16];
  float* out = (float*)d_out;
  char* ws = (char*)d_ws;

  // ws layout (bytes):
  //   xb2   @ 0          : T*B*512 bf16   = 33,554,432
  //   y1    @ 33554432   : T*B*512 bf16   = 33,554,432
  //   hbA   @ 67108864   : 513*B*512 bf16 = 33,619,968
  //   hbB   @ 100728832  : 33,619,968
  //   flags @ 134348800  : flagsA[4 planes][64 blk][32 u32] = 32KB, flagsB +32KB
  unsigned short* xb2 = (unsigned short*)ws;
  unsigned short* y1b = (unsigned short*)(ws + 33554432);
  unsigned short* hbA = (unsigned short*)(ws + 67108864);
  unsigned short* hbB = (unsigned short*)(ws + 100728832);
  unsigned int* flagsA = (unsigned int*)(ws + 134348800);
  unsigned int* flagsB = (unsigned int*)(ws + 134348800 + 32768);

  // zero: h slot 0 for both chains + flags
  hipMemsetAsync(ws + 67108864, 0, 65536, stream);
  hipMemsetAsync(ws + 100728832, 0, 65536, stream);
  hipMemsetAsync(ws + 134348800, 0, 65536, stream);

  cvt_x2_kernel<<<8192, 256, 0, stream>>>(x, xb2);

  fused_glow_kernel<<<128, 256, 0, stream>>>(
      x, xb2,
      // chain A = s2 + cg2
      s2_Wih, s2_Whh, s2_bih, s2_bhh, s2_Wo, s2_bo, cg2_W, cg2_b,
      // chain B = s1 + cg1
      s1_Wih, s1_Whh, s1_bih, s1_bhh, s1_Wo, s1_bo, cg1_W, cg1_b,
      y1b, out, hbA, hbB, flagsA, flagsB);
}